// Round 9
// baseline (185.646 us; speedup 1.0000x reference)
//
#include <hip/hip_runtime.h>

typedef _Float16 f16x8 __attribute__((ext_vector_type(8)));
typedef short s16x4 __attribute__((ext_vector_type(4)));
typedef float f32x4 __attribute__((ext_vector_type(4)));

#define MFMA_K32(a, b, c) __builtin_amdgcn_mfma_f32_16x16x32_f16(a, b, c, 0, 0, 0)
#define MFMA_BF(a, b, c)  __builtin_amdgcn_mfma_f32_16x16x16bf16_1k(a, b, c, 0, 0, 0)

// B=8, N=3136, C=256, Ci=128, M=1568, NT=25088 rows. I/O fp32.
// Fragment-major internals (every hot load = base + lane*16B):
//   theta_f/y_f [1568 tiles][kc 4][lane 64][8]      (f16)
//   phi_f [8][chunk 49][kvt 2][kc 4][lane 64][8]    (f16)
//   g_f   [8][chunk 49][ct 8][lane 64][8]           (bf16; j = h*4 + jj)
//   wt_f  [3][ct 8][kc 8][lane 64][8], wf_f [2][ct 8][kc 4][lane 64][8]
// Softmax: static-shift (no online max): p = exp2(s*log2e - 104), P/V bf16.
// Attention: Q-split, wave owns 2 m-tiles (32 Q rows) -> LDS read traffic
// per Q-row halved vs R8 (LDS port was the R8 bound: 8 waves x 16 b128 x
// 12cyc = 1536 cyc/chunk/CU).

__device__ __forceinline__ f16x8 ld8f(const float* __restrict__ p) {
    f32x4 a = *(const f32x4*)p;
    f32x4 b = *(const f32x4*)(p + 4);
    f16x8 r;
    r[0] = (_Float16)a[0]; r[1] = (_Float16)a[1];
    r[2] = (_Float16)a[2]; r[3] = (_Float16)a[3];
    r[4] = (_Float16)b[0]; r[5] = (_Float16)b[1];
    r[6] = (_Float16)b[2]; r[7] = (_Float16)b[3];
    return r;
}
__device__ __forceinline__ unsigned f2bf_rne(float f) {
    unsigned u = __float_as_uint(f);
    return (u + 0x7FFFu + ((u >> 16) & 1u)) >> 16;
}
__device__ __forceinline__ int bfpack_rtz(float lo, float hi) {
    return (int)((__float_as_uint(hi) & 0xFFFF0000u) | (__float_as_uint(lo) >> 16));
}

// ---------------------------------------------------------------------------
// Prep: weights fp32 -> f16, fragment-major.  grid 512, block 256.
// ---------------------------------------------------------------------------
__global__ void k_prep(const float* __restrict__ wt, const float* __restrict__ wp,
                       const float* __restrict__ wg, const float* __restrict__ wf,
                       _Float16* __restrict__ wt_f, _Float16* __restrict__ wf_f) {
    int i = blockIdx.x * 256 + threadIdx.x;  // 0..131071
    int w = i >> 15, idx = i & 32767;
    if (w < 3) {
        const float* src = (w == 0) ? wt : (w == 1) ? wp : wg;
        int k = idx >> 7, n = idx & 127;
        int ct = n >> 4, tt = n & 15, kc = k >> 5, qq = (k >> 3) & 3, jj = k & 7;
        wt_f[((w * 8 + ct) * 8 + kc) * 512 + (qq * 16 + tt) * 8 + jj] = (_Float16)src[idx];
    } else {
        int k = idx >> 8, n = idx & 255;
        int cb = n >> 7, ct = (n >> 4) & 7, tt = n & 15;
        int kc = k >> 5, qq = (k >> 3) & 3, jj = k & 7;
        wf_f[((cb * 8 + ct) * 4 + kc) * 512 + (qq * 16 + tt) * 8 + jj] = (_Float16)wf[idx];
    }
}

// ---------------------------------------------------------------------------
// Fused projections; maxpool(2) fused; fragment-major outputs.
// grid 784, block 128 (2 waves x 16 rows).
// ---------------------------------------------------------------------------
__global__ __launch_bounds__(128) void k_proj(
    const float* __restrict__ x,        // [25088][256] fp32
    const _Float16* __restrict__ wt_f,  // [3][8][8][512]
    _Float16* __restrict__ theta_f,     // [1568][2048]
    _Float16* __restrict__ phi_f,       // [8][49][4096]
    short* __restrict__ g_f)            // [8][49][4096] bf16
{
    const int r0   = blockIdx.x * 32;
    const int wave = threadIdx.x >> 6;
    const int lane = threadIdx.x & 63;
    const int q = lane >> 4, t = lane & 15;

    const int mrow = r0 + wave * 16 + t;
    f16x8 af[8];
#pragma unroll
    for (int kc = 0; kc < 8; ++kc)
        af[kc] = ld8f(x + mrow * 256 + kc * 32 + q * 8);

    const f32x4 zero = {0.f, 0.f, 0.f, 0.f};
    f32x4 acc[3][8];
#pragma unroll
    for (int w = 0; w < 3; ++w)
#pragma unroll
        for (int ct = 0; ct < 8; ++ct) acc[w][ct] = zero;

#pragma unroll
    for (int w = 0; w < 3; ++w)
#pragma unroll
        for (int ct = 0; ct < 8; ++ct) {
            const _Float16* Wc = wt_f + ((w * 8 + ct) * 8) * 512 + lane * 8;
#pragma unroll
            for (int kc = 0; kc < 8; ++kc)
                acc[w][ct] = MFMA_K32(af[kc], *(const f16x8*)(Wc + kc * 512), acc[w][ct]);
        }

    // theta -> fragment-major tile
    _Float16* tb = theta_f + (blockIdx.x * 2 + wave) * 2048;
#pragma unroll
    for (int ct = 0; ct < 8; ++ct) {
        const int off = (ct >> 1) * 512 + ((ct & 1) * 2 + (t >> 3)) * 128 + (t & 7);
#pragma unroll
        for (int r = 0; r < 4; ++r)
            tb[off + (q * 4 + r) * 8] = (_Float16)acc[0][ct][r];
    }

    const int b     = blockIdx.x / 98;
    const int mIdx  = blockIdx.x % 98;
    const int chunk = mIdx >> 1;
    const int h     = mIdx & 1;          // bit4 of pooled row within chunk
    const int ttp   = wave * 8 + q * 2;  // kv' = pooled row & 15 (even)

    _Float16* pcb = phi_f + (b * 49 + chunk) * 4096;
#pragma unroll
    for (int ct = 0; ct < 8; ++ct) {
        const int kc = ct >> 1;
        const int qq = (ct & 1) * 2 + (t >> 3);
        const int j  = t & 7;
        const int off = (h * 4 + kc) * 512 + (qq * 16 + ttp) * 8 + j;
        pcb[off]     = (_Float16)fmaxf(acc[1][ct][0], acc[1][ct][1]);
        pcb[off + 8] = (_Float16)fmaxf(acc[1][ct][2], acc[1][ct][3]);
    }

    // g: B-frag of 16x16x16: lane = qv*16 + ci15, j8 = h*4 + (kv'&3)
    short* gcb = g_f + (b * 49 + chunk) * 4096;
    const int qv  = wave * 2 + (q >> 1);   // kv' >> 2
    const int jj0 = (q & 1) * 2;           // kv' & 3 (even)
#pragma unroll
    for (int ct = 0; ct < 8; ++ct) {
        unsigned lo = f2bf_rne(fmaxf(acc[2][ct][0], acc[2][ct][1]));
        unsigned hi = f2bf_rne(fmaxf(acc[2][ct][2], acc[2][ct][3]));
        *(unsigned*)(gcb + ct * 512 + (qv * 16 + t) * 8 + h * 4 + jj0) = lo | (hi << 16);
    }
}

// ---------------------------------------------------------------------------
// Attention: Q-split, 2 m-tiles per wave (32 Q rows). Block = 2 waves =
// 4 m-tiles; KV chunk (16KB) double-buffered in LDS, staged cooperatively
// (wave w stages half), prefetch into regs overlaps compute; one barrier
// pair per chunk.  grid 392 (8 batches x 49), block 128.
// ---------------------------------------------------------------------------
__global__ __launch_bounds__(128) void k_attn(
    const _Float16* __restrict__ theta_f,  // [1568][2048]
    const _Float16* __restrict__ phi_f,    // [8][49][4096]
    const short* __restrict__ g_f,         // [8][49][4096] bf16
    _Float16* __restrict__ y_f)            // [1568][2048]
{
    const int blk  = blockIdx.x;          // 392 = 8 batches x 49
    const int b    = blk & 7;             // XCD affinity
    const int blkm = blk >> 3;            // 0..48
    const int wave = threadIdx.x >> 6;    // 0..1
    const int lane = threadIdx.x & 63;
    const int q = lane >> 4, t = lane & 15;

    __shared__ __align__(16) _Float16 kv[2][8192];  // 32 KB: [phi 4096 | g 4096]

    const int tIdx0 = b * 196 + blkm * 4 + wave * 2;  // this wave's 2 m-tiles
    const _Float16* ph = phi_f + b * 200704;
    const _Float16* gt = (const _Float16*)(g_f + b * 200704);

    // Q fragments for both m-tiles, register-resident for the whole scan
    f16x8 qf[2][4];
#pragma unroll
    for (int mt = 0; mt < 2; ++mt)
#pragma unroll
        for (int kc = 0; kc < 4; ++kc)
            qf[mt][kc] = *(const f16x8*)(theta_f + (tIdx0 + mt) * 2048 + kc * 512 + lane * 8);

    const f32x4 zero = {0.f, 0.f, 0.f, 0.f};
    f32x4 o[2][8];
#pragma unroll
    for (int mt = 0; mt < 2; ++mt)
#pragma unroll
        for (int ct = 0; ct < 8; ++ct) o[mt][ct] = zero;
    float lsum[2] = {0.f, 0.f};
    const float L2E = 1.44269504f, SHIFT = 104.0f;

    // staging: wave 0 -> phi half (8KB), wave 1 -> g half (8KB)
    const _Float16* src0 = (wave == 0) ? ph : gt;
    const int doff = wave * 4096;

    f16x8 sr[8];
#pragma unroll
    for (int j = 0; j < 8; ++j)
        sr[j] = *(const f16x8*)(src0 + j * 512 + lane * 8);
#pragma unroll
    for (int j = 0; j < 8; ++j)
        *(f16x8*)(&kv[0][doff + j * 512 + lane * 8]) = sr[j];
    __syncthreads();

    for (int i = 0; i < 49; ++i) {
        if (i + 1 < 49) {
            const _Float16* s = src0 + (i + 1) * 4096;
#pragma unroll
            for (int j = 0; j < 8; ++j)
                sr[j] = *(const f16x8*)(s + j * 512 + lane * 8);
        }

        const _Float16* buf = &kv[i & 1][0];
        // S^T = phi @ theta^T for both m-tiles (KV on C rows)
        f32x4 st00 = zero, st01 = zero, st10 = zero, st11 = zero;
#pragma unroll
        for (int kc = 0; kc < 4; ++kc) {
            f16x8 a0 = *(const f16x8*)(buf + kc * 512 + lane * 8);
            f16x8 a1 = *(const f16x8*)(buf + (4 + kc) * 512 + lane * 8);
            st00 = MFMA_K32(a0, qf[0][kc], st00);
            st10 = MFMA_K32(a1, qf[0][kc], st10);
            st01 = MFMA_K32(a0, qf[1][kc], st01);
            st11 = MFMA_K32(a1, qf[1][kc], st11);
        }

        // p = exp2(s*log2e - SHIFT); pack P to bf16 (A-layout of 16x16x16)
        s16x4 pa[2][2];
#pragma unroll
        for (int mt = 0; mt < 2; ++mt) {
            f32x4 s0 = mt ? st01 : st00;
            f32x4 s1 = mt ? st11 : st10;
            f32x4 p0, p1;
#pragma unroll
            for (int r = 0; r < 4; ++r) {
                p0[r] = exp2f(s0[r] * L2E - SHIFT);
                p1[r] = exp2f(s1[r] * L2E - SHIFT);
            }
            lsum[mt] += ((p0[0] + p0[1]) + (p0[2] + p0[3]))
                      + ((p1[0] + p1[1]) + (p1[2] + p1[3]));
            union { int i2[2]; s16x4 v; } u0, u1;
            u0.i2[0] = bfpack_rtz(p0[0], p0[1]);
            u0.i2[1] = bfpack_rtz(p0[2], p0[3]);
            u1.i2[0] = bfpack_rtz(p1[0], p1[1]);
            u1.i2[1] = bfpack_rtz(p1[2], p1[3]);
            pa[mt][0] = u0.v;
            pa[mt][1] = u1.v;
        }

        // PV: both m-tiles share each V read (b128 = both kv-halves)
#pragma unroll
        for (int ct = 0; ct < 8; ++ct) {
            union { f16x8 f; s16x4 s[2]; } uv;
            uv.f = *(const f16x8*)(buf + 4096 + ct * 512 + lane * 8);
            o[0][ct] = MFMA_BF(pa[0][0], uv.s[0], o[0][ct]);
            o[0][ct] = MFMA_BF(pa[0][1], uv.s[1], o[0][ct]);
            o[1][ct] = MFMA_BF(pa[1][0], uv.s[0], o[1][ct]);
            o[1][ct] = MFMA_BF(pa[1][1], uv.s[1], o[1][ct]);
        }

        if (i + 1 < 49) {
            _Float16* d = &kv[(i + 1) & 1][doff];
#pragma unroll
            for (int j = 0; j < 8; ++j)
                *(f16x8*)(d + j * 512 + lane * 8) = sr[j];
        }
        __syncthreads();
    }

    // l per Q-row; O rows are 4q+r -> per-row inv(l); store fragment-major
#pragma unroll
    for (int mt = 0; mt < 2; ++mt) {
        float lf = lsum[mt];
        lf += __shfl_xor(lf, 16);
        lf += __shfl_xor(lf, 32);
        float inv[4];
#pragma unroll
        for (int r = 0; r < 4; ++r) inv[r] = 1.0f / __shfl(lf, q * 4 + r);

        _Float16* yb = y_f + (tIdx0 + mt) * 2048;
#pragma unroll
        for (int ct = 0; ct < 8; ++ct) {
            const int off = (ct >> 1) * 512 + (2 * (ct & 1) + (t >> 3)) * 128 + (t & 7);
#pragma unroll
            for (int r = 0; r < 4; ++r)
                yb[off + (4 * q + r) * 8] = (_Float16)(o[mt][ct][r] * inv[r]);
        }
    }
}

// ---------------------------------------------------------------------------
// Final: out = x + y @ w_final (fp32), coalesced loads + LDS-transposed
// epilogue.  grid (392, 2), block 256.
// ---------------------------------------------------------------------------
__global__ __launch_bounds__(256) void k_final(
    const _Float16* __restrict__ y_f,   // [1568][2048]
    const _Float16* __restrict__ wf_f,  // [2][8][4][512]
    const float* __restrict__ x,        // [25088][256]
    float* __restrict__ out)            // [25088][256]
{
    const int r0   = blockIdx.x * 64;
    const int cb   = blockIdx.y;
    const int wave = threadIdx.x >> 6;
    const int lane = threadIdx.x & 63;
    const int q = lane >> 4, t = lane & 15;

    __shared__ float t_lds[4][16][132];

    const int tile = blockIdx.x * 4 + wave;
    f16x8 af[4];
#pragma unroll
    for (int kc = 0; kc < 4; ++kc)
        af[kc] = *(const f16x8*)(y_f + tile * 2048 + kc * 512 + lane * 8);

    const f32x4 zero = {0.f, 0.f, 0.f, 0.f};
    f32x4 acc[8];
#pragma unroll
    for (int ct = 0; ct < 8; ++ct) acc[ct] = zero;
#pragma unroll
    for (int ct = 0; ct < 8; ++ct) {
        const _Float16* Wc = wf_f + ((cb * 8 + ct) * 4) * 512 + lane * 8;
#pragma unroll
        for (int kc = 0; kc < 4; ++kc)
            acc[ct] = MFMA_K32(af[kc], *(const f16x8*)(Wc + kc * 512), acc[ct]);
    }

#pragma unroll
    for (int ct = 0; ct < 8; ++ct)
#pragma unroll
        for (int r = 0; r < 4; ++r)
            t_lds[wave][q * 4 + r][ct * 16 + t] = acc[ct][r];

    const int R0 = r0 + wave * 16;
#pragma unroll
    for (int p = 0; p < 4; ++p) {
        const int rr = p * 4 + q;
        const int c  = t * 8;
        f32x4 v0 = *(const f32x4*)&t_lds[wave][rr][c];
        f32x4 v1 = *(const f32x4*)&t_lds[wave][rr][c + 4];
        const float* xp = x + (R0 + rr) * 256 + cb * 128 + c;
        float* op = out + (R0 + rr) * 256 + cb * 128 + c;
        v0 += *(const f32x4*)xp;
        v1 += *(const f32x4*)(xp + 4);
        *(f32x4*)op = v0;
        *(f32x4*)(op + 4) = v1;
    }
}

// ---------------------------------------------------------------------------
extern "C" void kernel_launch(void* const* d_in, const int* in_sizes, int n_in,
                              void* d_out, int out_size, void* d_ws, size_t ws_size,
                              hipStream_t stream) {
    const float* x  = (const float*)d_in[0];
    const float* wt = (const float*)d_in[1];
    const float* wp = (const float*)d_in[2];
    const float* wg = (const float*)d_in[3];
    const float* wf = (const float*)d_in[4];
    float* out = (float*)d_out;

    _Float16* ws      = (_Float16*)d_ws;
    _Float16* wt_f    = ws;               //  98304
    _Float16* wf_f    = ws + 98304;       //  32768
    _Float16* theta_f = ws + 131072;      //  3211264
    _Float16* phi_f   = ws + 3342336;     //  1605632
    short*    g_f     = (short*)(ws + 4947968);  // 1605632
    _Float16* y_f     = ws + 6553600;     //  3211264
    // total 9764864 halves = ~18.6 MB

    k_prep <<<dim3(512),    256, 0, stream>>>(wt, wp, wg, wf, wt_f, wf_f);
    k_proj <<<dim3(784),    128, 0, stream>>>(x, wt_f, theta_f, phi_f, g_f);
    k_attn <<<dim3(392),    128, 0, stream>>>(theta_f, phi_f, g_f, y_f);
    k_final<<<dim3(392, 2), 256, 0, stream>>>(y_f, wf_f, x, out);
}

// Round 10
// 176.429 us; speedup vs baseline: 1.0522x; 1.0522x over previous
//
#include <hip/hip_runtime.h>

typedef _Float16 f16x8 __attribute__((ext_vector_type(8)));
typedef short s16x4 __attribute__((ext_vector_type(4)));
typedef float f32x4 __attribute__((ext_vector_type(4)));

#define MFMA_K32(a, b, c) __builtin_amdgcn_mfma_f32_16x16x32_f16(a, b, c, 0, 0, 0)
#define MFMA_BF(a, b, c)  __builtin_amdgcn_mfma_f32_16x16x16bf16_1k(a, b, c, 0, 0, 0)

// B=8, N=3136, C=256, Ci=128, M=1568, NT=25088 rows. I/O fp32.
// Fragment-major internals (every hot load = base + lane*16B):
//   theta_f/y_f [1568 tiles][kc 4][lane 64][8]      (f16)
//   phi_f [8][chunk 49][kvt 2][kc 4][lane 64][8]    (f16)
//   g_f   [8][chunk 49][ct 8][lane 64][8]           (bf16)
//   wt_f  [3][ct 8][kc 8][lane 64][8], wf_f [2][ct 8][kc 4][lane 64][8]
// Softmax: static-shift (no online max): p = exp2(s*log2e - 104), P/V bf16.
// Attention: LDS-port-bound -> 4 waves x 2 m-tiles per block (128 Q rows),
// grid 200 = 8 batches x 25 (1 block/CU, no round quantization).

__device__ __forceinline__ f16x8 ld8f(const float* __restrict__ p) {
    f32x4 a = *(const f32x4*)p;
    f32x4 b = *(const f32x4*)(p + 4);
    f16x8 r;
    r[0] = (_Float16)a[0]; r[1] = (_Float16)a[1];
    r[2] = (_Float16)a[2]; r[3] = (_Float16)a[3];
    r[4] = (_Float16)b[0]; r[5] = (_Float16)b[1];
    r[6] = (_Float16)b[2]; r[7] = (_Float16)b[3];
    return r;
}
__device__ __forceinline__ unsigned f2bf_rne(float f) {
    unsigned u = __float_as_uint(f);
    return (u + 0x7FFFu + ((u >> 16) & 1u)) >> 16;
}
__device__ __forceinline__ int bfpack_rtz(float lo, float hi) {
    return (int)((__float_as_uint(hi) & 0xFFFF0000u) | (__float_as_uint(lo) >> 16));
}

// ---------------------------------------------------------------------------
// Prep: weights fp32 -> f16, fragment-major.  grid 512, block 256.
// ---------------------------------------------------------------------------
__global__ void k_prep(const float* __restrict__ wt, const float* __restrict__ wp,
                       const float* __restrict__ wg, const float* __restrict__ wf,
                       _Float16* __restrict__ wt_f, _Float16* __restrict__ wf_f) {
    int i = blockIdx.x * 256 + threadIdx.x;  // 0..131071
    int w = i >> 15, idx = i & 32767;
    if (w < 3) {
        const float* src = (w == 0) ? wt : (w == 1) ? wp : wg;
        int k = idx >> 7, n = idx & 127;
        int ct = n >> 4, tt = n & 15, kc = k >> 5, qq = (k >> 3) & 3, jj = k & 7;
        wt_f[((w * 8 + ct) * 8 + kc) * 512 + (qq * 16 + tt) * 8 + jj] = (_Float16)src[idx];
    } else {
        int k = idx >> 8, n = idx & 255;
        int cb = n >> 7, ct = (n >> 4) & 7, tt = n & 15;
        int kc = k >> 5, qq = (k >> 3) & 3, jj = k & 7;
        wf_f[((cb * 8 + ct) * 4 + kc) * 512 + (qq * 16 + tt) * 8 + jj] = (_Float16)wf[idx];
    }
}

// ---------------------------------------------------------------------------
// Fused projections; maxpool(2) fused; fragment-major outputs.
// grid 784, block 128 (2 waves x 16 rows).
// ---------------------------------------------------------------------------
__global__ __launch_bounds__(128) void k_proj(
    const float* __restrict__ x,        // [25088][256] fp32
    const _Float16* __restrict__ wt_f,  // [3][8][8][512]
    _Float16* __restrict__ theta_f,     // [1568][2048]
    _Float16* __restrict__ phi_f,       // [8][49][4096]
    short* __restrict__ g_f)            // [8][49][4096] bf16
{
    const int r0   = blockIdx.x * 32;
    const int wave = threadIdx.x >> 6;
    const int lane = threadIdx.x & 63;
    const int q = lane >> 4, t = lane & 15;

    const int mrow = r0 + wave * 16 + t;
    f16x8 af[8];
#pragma unroll
    for (int kc = 0; kc < 8; ++kc)
        af[kc] = ld8f(x + mrow * 256 + kc * 32 + q * 8);

    const f32x4 zero = {0.f, 0.f, 0.f, 0.f};
    f32x4 acc[3][8];
#pragma unroll
    for (int w = 0; w < 3; ++w)
#pragma unroll
        for (int ct = 0; ct < 8; ++ct) acc[w][ct] = zero;

#pragma unroll
    for (int w = 0; w < 3; ++w)
#pragma unroll
        for (int ct = 0; ct < 8; ++ct) {
            const _Float16* Wc = wt_f + ((w * 8 + ct) * 8) * 512 + lane * 8;
#pragma unroll
            for (int kc = 0; kc < 8; ++kc)
                acc[w][ct] = MFMA_K32(af[kc], *(const f16x8*)(Wc + kc * 512), acc[w][ct]);
        }

    // theta -> fragment-major tile
    _Float16* tb = theta_f + (blockIdx.x * 2 + wave) * 2048;
#pragma unroll
    for (int ct = 0; ct < 8; ++ct) {
        const int off = (ct >> 1) * 512 + ((ct & 1) * 2 + (t >> 3)) * 128 + (t & 7);
#pragma unroll
        for (int r = 0; r < 4; ++r)
            tb[off + (q * 4 + r) * 8] = (_Float16)acc[0][ct][r];
    }

    const int b     = blockIdx.x / 98;
    const int mIdx  = blockIdx.x % 98;
    const int chunk = mIdx >> 1;
    const int h     = mIdx & 1;          // bit4 of pooled row within chunk
    const int ttp   = wave * 8 + q * 2;  // kv' = pooled row & 15 (even)

    _Float16* pcb = phi_f + (b * 49 + chunk) * 4096;
#pragma unroll
    for (int ct = 0; ct < 8; ++ct) {
        const int kc = ct >> 1;
        const int qq = (ct & 1) * 2 + (t >> 3);
        const int j  = t & 7;
        const int off = (h * 4 + kc) * 512 + (qq * 16 + ttp) * 8 + j;
        pcb[off]     = (_Float16)fmaxf(acc[1][ct][0], acc[1][ct][1]);
        pcb[off + 8] = (_Float16)fmaxf(acc[1][ct][2], acc[1][ct][3]);
    }

    // g: B-frag of 16x16x16: lane = qv*16 + ci15, j8 = h*4 + (kv'&3)
    short* gcb = g_f + (b * 49 + chunk) * 4096;
    const int qv  = wave * 2 + (q >> 1);   // kv' >> 2
    const int jj0 = (q & 1) * 2;           // kv' & 3 (even)
#pragma unroll
    for (int ct = 0; ct < 8; ++ct) {
        unsigned lo = f2bf_rne(fmaxf(acc[2][ct][0], acc[2][ct][1]));
        unsigned hi = f2bf_rne(fmaxf(acc[2][ct][2], acc[2][ct][3]));
        *(unsigned*)(gcb + ct * 512 + (qv * 16 + t) * 8 + h * 4 + jj0) = lo | (hi << 16);
    }
}

// ---------------------------------------------------------------------------
// Attention: Q-split, 4 waves x 2 m-tiles (128 Q rows per block). KV chunk
// (16KB) double-buffered in LDS, staged cooperatively (each wave 4KB),
// prefetch into regs overlaps compute; one barrier per chunk.
// grid 200 (8 batches x 25 blocks), block 256. Last block per batch has
// only 4 tiles -> dt=0 duplicates tile per wave (benign same-wave WAW).
// ---------------------------------------------------------------------------
__global__ __launch_bounds__(256) void k_attn(
    const _Float16* __restrict__ theta_f,  // [1568][2048]
    const _Float16* __restrict__ phi_f,    // [8][49][4096]
    const short* __restrict__ g_f,         // [8][49][4096] bf16
    _Float16* __restrict__ y_f)            // [1568][2048]
{
    const int blk  = blockIdx.x;          // 200 = 8 batches x 25
    const int b    = blk & 7;             // XCD affinity
    const int blkm = blk >> 3;            // 0..24
    const int wave = threadIdx.x >> 6;    // 0..3
    const int lane = threadIdx.x & 63;
    const int q = lane >> 4, t = lane & 15;

    __shared__ __align__(16) _Float16 kv[2][8192];  // 32 KB: [phi 4096 | g 4096]

    int t0, dt;
    if (blkm < 24) { t0 = b * 196 + blkm * 8 + wave * 2; dt = 1; }
    else           { t0 = b * 196 + 192 + wave;          dt = 0; }

    const _Float16* ph = phi_f + b * 200704;
    const _Float16* gt = (const _Float16*)(g_f + b * 200704);

    // Q fragments for both m-tiles, register-resident for the whole scan
    f16x8 qf[2][4];
#pragma unroll
    for (int mt = 0; mt < 2; ++mt)
#pragma unroll
        for (int kc = 0; kc < 4; ++kc)
            qf[mt][kc] = *(const f16x8*)(theta_f + (t0 + mt * dt) * 2048 + kc * 512 + lane * 8);

    const f32x4 zero = {0.f, 0.f, 0.f, 0.f};
    f32x4 o[2][8];
#pragma unroll
    for (int mt = 0; mt < 2; ++mt)
#pragma unroll
        for (int ct = 0; ct < 8; ++ct) o[mt][ct] = zero;
    float lsum[2] = {0.f, 0.f};
    const float L2E = 1.44269504f, SHIFT = 104.0f;

    // staging: wave w stages 4KB quarter of the 16KB chunk
    const _Float16* src0 = (wave < 2) ? (ph + wave * 2048) : (gt + (wave - 2) * 2048);
    const int doff = wave * 2048;

    f16x8 sr[4];
#pragma unroll
    for (int j = 0; j < 4; ++j)
        sr[j] = *(const f16x8*)(src0 + j * 512 + lane * 8);
#pragma unroll
    for (int j = 0; j < 4; ++j)
        *(f16x8*)(&kv[0][doff + j * 512 + lane * 8]) = sr[j];
    __syncthreads();

    for (int i = 0; i < 49; ++i) {
        if (i + 1 < 49) {
            const _Float16* s = src0 + (i + 1) * 4096;
#pragma unroll
            for (int j = 0; j < 4; ++j)
                sr[j] = *(const f16x8*)(s + j * 512 + lane * 8);
        }

        const _Float16* buf = &kv[i & 1][0];
        // S^T = phi @ theta^T for both m-tiles (KV on C rows)
        f32x4 st00 = zero, st01 = zero, st10 = zero, st11 = zero;
#pragma unroll
        for (int kc = 0; kc < 4; ++kc) {
            f16x8 a0 = *(const f16x8*)(buf + kc * 512 + lane * 8);
            f16x8 a1 = *(const f16x8*)(buf + (4 + kc) * 512 + lane * 8);
            st00 = MFMA_K32(a0, qf[0][kc], st00);
            st10 = MFMA_K32(a1, qf[0][kc], st10);
            st01 = MFMA_K32(a0, qf[1][kc], st01);
            st11 = MFMA_K32(a1, qf[1][kc], st11);
        }

        // p = exp2(s*log2e - SHIFT); pack P to bf16 (A-layout of 16x16x16)
        s16x4 pa[2][2];
#pragma unroll
        for (int mt = 0; mt < 2; ++mt) {
            f32x4 s0 = mt ? st01 : st00;
            f32x4 s1 = mt ? st11 : st10;
            f32x4 p0, p1;
#pragma unroll
            for (int r = 0; r < 4; ++r) {
                p0[r] = exp2f(s0[r] * L2E - SHIFT);
                p1[r] = exp2f(s1[r] * L2E - SHIFT);
            }
            lsum[mt] += ((p0[0] + p0[1]) + (p0[2] + p0[3]))
                      + ((p1[0] + p1[1]) + (p1[2] + p1[3]));
            union { int i2[2]; s16x4 v; } u0, u1;
            u0.i2[0] = bfpack_rtz(p0[0], p0[1]);
            u0.i2[1] = bfpack_rtz(p0[2], p0[3]);
            u1.i2[0] = bfpack_rtz(p1[0], p1[1]);
            u1.i2[1] = bfpack_rtz(p1[2], p1[3]);
            pa[mt][0] = u0.v;
            pa[mt][1] = u1.v;
        }

        // PV: both m-tiles share each V read (b128 = both kv-halves)
#pragma unroll
        for (int ct = 0; ct < 8; ++ct) {
            union { f16x8 f; s16x4 s[2]; } uv;
            uv.f = *(const f16x8*)(buf + 4096 + ct * 512 + lane * 8);
            o[0][ct] = MFMA_BF(pa[0][0], uv.s[0], o[0][ct]);
            o[0][ct] = MFMA_BF(pa[0][1], uv.s[1], o[0][ct]);
            o[1][ct] = MFMA_BF(pa[1][0], uv.s[0], o[1][ct]);
            o[1][ct] = MFMA_BF(pa[1][1], uv.s[1], o[1][ct]);
        }

        if (i + 1 < 49) {
            _Float16* d = &kv[(i + 1) & 1][doff];
#pragma unroll
            for (int j = 0; j < 4; ++j)
                *(f16x8*)(d + j * 512 + lane * 8) = sr[j];
        }
        __syncthreads();
    }

    // l per Q-row; O rows are 4q+r -> per-row inv(l); store fragment-major
#pragma unroll
    for (int mt = 0; mt < 2; ++mt) {
        float lf = lsum[mt];
        lf += __shfl_xor(lf, 16);
        lf += __shfl_xor(lf, 32);
        float inv[4];
#pragma unroll
        for (int r = 0; r < 4; ++r) inv[r] = 1.0f / __shfl(lf, q * 4 + r);

        _Float16* yb = y_f + (t0 + mt * dt) * 2048;
#pragma unroll
        for (int ct = 0; ct < 8; ++ct) {
            const int off = (ct >> 1) * 512 + (2 * (ct & 1) + (t >> 3)) * 128 + (t & 7);
#pragma unroll
            for (int r = 0; r < 4; ++r)
                yb[off + (4 * q + r) * 8] = (_Float16)(o[mt][ct][r] * inv[r]);
        }
    }
}

// ---------------------------------------------------------------------------
// Final: out = x + y @ w_final (fp32), coalesced loads + LDS-transposed
// epilogue.  grid (392, 2), block 256.
// ---------------------------------------------------------------------------
__global__ __launch_bounds__(256) void k_final(
    const _Float16* __restrict__ y_f,   // [1568][2048]
    const _Float16* __restrict__ wf_f,  // [2][8][4][512]
    const float* __restrict__ x,        // [25088][256]
    float* __restrict__ out)            // [25088][256]
{
    const int r0   = blockIdx.x * 64;
    const int cb   = blockIdx.y;
    const int wave = threadIdx.x >> 6;
    const int lane = threadIdx.x & 63;
    const int q = lane >> 4, t = lane & 15;

    __shared__ float t_lds[4][16][132];

    const int tile = blockIdx.x * 4 + wave;
    f16x8 af[4];
#pragma unroll
    for (int kc = 0; kc < 4; ++kc)
        af[kc] = *(const f16x8*)(y_f + tile * 2048 + kc * 512 + lane * 8);

    const f32x4 zero = {0.f, 0.f, 0.f, 0.f};
    f32x4 acc[8];
#pragma unroll
    for (int ct = 0; ct < 8; ++ct) acc[ct] = zero;
#pragma unroll
    for (int ct = 0; ct < 8; ++ct) {
        const _Float16* Wc = wf_f + ((cb * 8 + ct) * 4) * 512 + lane * 8;
#pragma unroll
        for (int kc = 0; kc < 4; ++kc)
            acc[ct] = MFMA_K32(af[kc], *(const f16x8*)(Wc + kc * 512), acc[ct]);
    }

#pragma unroll
    for (int ct = 0; ct < 8; ++ct)
#pragma unroll
        for (int r = 0; r < 4; ++r)
            t_lds[wave][q * 4 + r][ct * 16 + t] = acc[ct][r];

    const int R0 = r0 + wave * 16;
#pragma unroll
    for (int p = 0; p < 4; ++p) {
        const int rr = p * 4 + q;
        const int c  = t * 8;
        f32x4 v0 = *(const f32x4*)&t_lds[wave][rr][c];
        f32x4 v1 = *(const f32x4*)&t_lds[wave][rr][c + 4];
        const float* xp = x + (R0 + rr) * 256 + cb * 128 + c;
        float* op = out + (R0 + rr) * 256 + cb * 128 + c;
        v0 += *(const f32x4*)xp;
        v1 += *(const f32x4*)(xp + 4);
        *(f32x4*)op = v0;
        *(f32x4*)(op + 4) = v1;
    }
}

// ---------------------------------------------------------------------------
extern "C" void kernel_launch(void* const* d_in, const int* in_sizes, int n_in,
                              void* d_out, int out_size, void* d_ws, size_t ws_size,
                              hipStream_t stream) {
    const float* x  = (const float*)d_in[0];
    const float* wt = (const float*)d_in[1];
    const float* wp = (const float*)d_in[2];
    const float* wg = (const float*)d_in[3];
    const float* wf = (const float*)d_in[4];
    float* out = (float*)d_out;

    _Float16* ws      = (_Float16*)d_ws;
    _Float16* wt_f    = ws;               //  98304
    _Float16* wf_f    = ws + 98304;       //  32768
    _Float16* theta_f = ws + 131072;      //  3211264
    _Float16* phi_f   = ws + 3342336;     //  1605632
    short*    g_f     = (short*)(ws + 4947968);  // 1605632
    _Float16* y_f     = ws + 6553600;     //  3211264
    // total 9764864 halves = ~18.6 MB

    k_prep <<<dim3(512),    256, 0, stream>>>(wt, wp, wg, wf, wt_f, wf_f);
    k_proj <<<dim3(784),    128, 0, stream>>>(x, wt_f, theta_f, phi_f, g_f);
    k_attn <<<dim3(200),    256, 0, stream>>>(theta_f, phi_f, g_f, y_f);
    k_final<<<dim3(392, 2), 256, 0, stream>>>(y_f, wf_f, x, out);
}